// Round 1
// baseline (1451.796 us; speedup 1.0000x reference)
//
#include <hip/hip_runtime.h>
#include <math.h>

#define C 128

// ---------------------------------------------------------------------------
// K0: row norms for embedding (anorm[N]) and memory bank (bnorm[M])
// ---------------------------------------------------------------------------
__global__ __launch_bounds__(256) void norms_kernel(
    const float* __restrict__ A, const float* __restrict__ Bk,
    float* __restrict__ anorm, float* __restrict__ bnorm, int N, int M) {
  int t = blockIdx.x * 256 + threadIdx.x;
  const float* src;
  float* dst;
  int r;
  if (t < M) { src = Bk; dst = bnorm; r = t; }
  else if (t < M + N) { src = A; dst = anorm; r = t - M; }
  else return;
  const float4* p = (const float4*)(src + (size_t)r * C);
  float acc = 0.0f;
#pragma unroll
  for (int kc = 0; kc < C / 4; ++kc) {
    float4 v = p[kc];
    acc += v.x * v.x + v.y * v.y + v.z * v.z + v.w * v.w;
  }
  dst[r] = acc;
}

// ---------------------------------------------------------------------------
// K1: NN search partial mins.  grid (N/64, 4).  Each block: 64 emb rows vs
// one quarter of the bank.  metric = bnorm[j] - 2*dot  (anorm added later).
// ---------------------------------------------------------------------------
__global__ __launch_bounds__(256) void nn_partial(
    const float* __restrict__ A, const float* __restrict__ Bk,
    const float* __restrict__ bnorm, float* __restrict__ pvals,
    int* __restrict__ pidx, int N, int M) {
  __shared__ float As[64][132];
  __shared__ float Bs[64][132];
  const int tid = threadIdx.x;
  const int ti = tid >> 4;   // 0..15 -> rows {ti+16i}
  const int tj = tid & 15;   // 0..15 -> cols {tj+16j}
  const int row0 = blockIdx.x * 64;
  const int mq = M >> 2;
  const int j0base = blockIdx.y * mq;

  for (int t = tid; t < 64 * 32; t += 256) {
    int r = t >> 5, kc = (t & 31) << 2;
    *(float4*)&As[r][kc] = *(const float4*)(A + (size_t)(row0 + r) * C + kc);
  }

  float minv[4] = {INFINITY, INFINITY, INFINITY, INFINITY};
  int mini[4] = {0, 0, 0, 0};

  for (int jt = 0; jt < mq; jt += 64) {
    const int j0 = j0base + jt;
    __syncthreads();
    for (int t = tid; t < 64 * 32; t += 256) {
      int r = t >> 5, kc = (t & 31) << 2;
      *(float4*)&Bs[r][kc] = *(const float4*)(Bk + (size_t)(j0 + r) * C + kc);
    }
    __syncthreads();

    float dot[4][4] = {};
#pragma unroll 4
    for (int kc = 0; kc < C; kc += 4) {
      float4 av[4], bv[4];
#pragma unroll
      for (int i = 0; i < 4; ++i) av[i] = *(const float4*)&As[ti + 16 * i][kc];
#pragma unroll
      for (int j = 0; j < 4; ++j) bv[j] = *(const float4*)&Bs[tj + 16 * j][kc];
#pragma unroll
      for (int i = 0; i < 4; ++i)
#pragma unroll
        for (int j = 0; j < 4; ++j)
          dot[i][j] += av[i].x * bv[j].x + av[i].y * bv[j].y +
                       av[i].z * bv[j].z + av[i].w * bv[j].w;
    }

#pragma unroll
    for (int j = 0; j < 4; ++j) {
      const int jj = j0 + tj + 16 * j;
      const float bn = bnorm[jj];
#pragma unroll
      for (int i = 0; i < 4; ++i) {
        float v = bn - 2.0f * dot[i][j];
        if (v < minv[i]) { minv[i] = v; mini[i] = jj; }  // ascending j: keeps first
      }
    }
  }

  __syncthreads();
  float* rv = &As[0][0];   // [64][16]
  int* ri = (int*)&Bs[0][0];
#pragma unroll
  for (int i = 0; i < 4; ++i) {
    int r = ti + 16 * i;
    rv[r * 16 + tj] = minv[i];
    ri[r * 16 + tj] = mini[i];
  }
  __syncthreads();
  if (tid < 64) {
    float bv = INFINITY;
    int bi_ = 0x7fffffff;
    for (int t = 0; t < 16; ++t) {
      float v = rv[tid * 16 + t];
      int ix = ri[tid * 16 + t];
      if (v < bv || (v == bv && ix < bi_)) { bv = v; bi_ = ix; }
    }
    pvals[(size_t)blockIdx.y * N + row0 + tid] = bv;
    pidx[(size_t)blockIdx.y * N + row0 + tid] = bi_;
  }
}

// ---------------------------------------------------------------------------
// K2: merge 4 partials, add anorm, sqrt -> patch_scores + locations
// ---------------------------------------------------------------------------
__global__ __launch_bounds__(256) void nn_merge(
    const float* __restrict__ anorm, const float* __restrict__ pvals,
    const int* __restrict__ pidx, float* __restrict__ ps,
    int* __restrict__ loc, int N) {
  int i = blockIdx.x * 256 + threadIdx.x;
  if (i >= N) return;
  float bv = INFINITY;
  int bi_ = 0x7fffffff;
  for (int p = 0; p < 4; ++p) {
    float v = pvals[(size_t)p * N + i];
    int ix = pidx[(size_t)p * N + i];
    if (v < bv || (v == bv && ix < bi_)) { bv = v; bi_ = ix; }
  }
  float d2 = anorm[i] + bv;
  ps[i] = sqrtf(fmaxf(d2, 1e-12f));
  loc[i] = bi_;
}

// ---------------------------------------------------------------------------
// K3: per-image argmax of patch scores (first occurrence)
// ---------------------------------------------------------------------------
__global__ __launch_bounds__(256) void batch_argmax(
    const float* __restrict__ ps, const int* __restrict__ loc,
    float* __restrict__ score, int* __restrict__ nnidx,
    int* __restrict__ maxrow) {
  const int b = blockIdx.x;
  __shared__ float sv[256];
  __shared__ int si[256];
  const int tid = threadIdx.x;
  float bv = -INFINITY;
  int bi_ = 0x7fffffff;
  for (int i = tid; i < 784; i += 256) {
    float v = ps[(size_t)b * 784 + i];
    if (v > bv) { bv = v; bi_ = i; }
  }
  sv[tid] = bv; si[tid] = bi_;
  __syncthreads();
  for (int s = 128; s > 0; s >>= 1) {
    if (tid < s) {
      if (sv[tid + s] > sv[tid] ||
          (sv[tid + s] == sv[tid] && si[tid + s] < si[tid])) {
        sv[tid] = sv[tid + s]; si[tid] = si[tid + s];
      }
    }
    __syncthreads();
  }
  if (tid == 0) {
    score[b] = sv[0];
    int p = si[0];
    maxrow[b] = b * 784 + p;
    nnidx[b] = loc[(size_t)b * 784 + p];
  }
}

// ---------------------------------------------------------------------------
// K4: per-image: distances nn_sample->bank, top-9 (9 argmin passes in LDS),
// softmax reweighting -> pred_score
// ---------------------------------------------------------------------------
__global__ __launch_bounds__(256) void batch_rescore(
    const float* __restrict__ emb, const float* __restrict__ Bk,
    const float* __restrict__ bnorm, const float* __restrict__ score,
    const int* __restrict__ nnidx, const int* __restrict__ maxrow,
    float* __restrict__ pred, int M) {
  const int b = blockIdx.x;
  __shared__ float d2s[16384];
  __shared__ float vec[C];
  __shared__ float sv[256];
  __shared__ int si[256];
  __shared__ float ds[9];
  __shared__ int sup[9];
  const int tid = threadIdx.x;
  const int nn = nnidx[b];
  if (tid < C) vec[tid] = Bk[(size_t)nn * C + tid];
  __syncthreads();
  const float nnorm = bnorm[nn];
  for (int j = tid; j < M; j += 256) {
    const float4* br = (const float4*)(Bk + (size_t)j * C);
    float dot = 0.0f;
#pragma unroll
    for (int kc = 0; kc < C / 4; ++kc) {
      float4 v = br[kc];
      float4 w = *(const float4*)&vec[kc * 4];
      dot += v.x * w.x + v.y * w.y + v.z * w.z + v.w * w.w;
    }
    d2s[j] = nnorm + bnorm[j] - 2.0f * dot;
  }
  __syncthreads();
  for (int s9 = 0; s9 < 9; ++s9) {
    float bv = INFINITY;
    int bi_ = 0x7fffffff;
    for (int j = tid; j < M; j += 256) {
      float v = d2s[j];
      if (v < bv) { bv = v; bi_ = j; }  // ascending j keeps first
    }
    sv[tid] = bv; si[tid] = bi_;
    __syncthreads();
    for (int s = 128; s > 0; s >>= 1) {
      if (tid < s) {
        if (sv[tid + s] < sv[tid] ||
            (sv[tid + s] == sv[tid] && si[tid + s] < si[tid])) {
          sv[tid] = sv[tid + s]; si[tid] = si[tid + s];
        }
      }
      __syncthreads();
    }
    if (tid == 0) { sup[s9] = si[0]; d2s[si[0]] = INFINITY; }
    __syncthreads();
  }
  // distances from max-patch feature to the 9 support rows
  if (tid < C) vec[tid] = emb[(size_t)maxrow[b] * C + tid];
  __syncthreads();
  if (tid < 9) {
    const float* br = Bk + (size_t)sup[tid] * C;
    float acc = 0.0f;
    for (int k = 0; k < C; ++k) {
      float d = vec[k] - br[k];
      acc += d * d;
    }
    ds[tid] = sqrtf(fmaxf(acc, 1e-12f));
  }
  __syncthreads();
  if (tid == 0) {
    float m = ds[0];
    for (int t = 1; t < 9; ++t) m = fmaxf(m, ds[t]);
    float sum = 0.0f, e0 = 0.0f;
    for (int t = 0; t < 9; ++t) {
      float e = expf(ds[t] - m);
      sum += e;
      if (t == 0) e0 = e;
    }
    pred[b] = (1.0f - e0 / sum) * score[b];
  }
}

// ---------------------------------------------------------------------------
// K5/K6: nearest-upsample 28x28 -> 224x224 fused with separable 33-tap
// Gaussian blur, reflect padding.  grid (224 rows, B images).
// ---------------------------------------------------------------------------
__global__ __launch_bounds__(256) void blur_h(const float* __restrict__ ps,
                                              float* __restrict__ tmp) {
  const int y = blockIdx.x, b = blockIdx.y;
  __shared__ float g[33];
  __shared__ float row28[28];
  __shared__ float gsum_s;
  const int tid = threadIdx.x;
  if (tid < 33) {
    float d = (float)tid - 16.0f;
    g[tid] = expf(-(d * d) * (1.0f / 32.0f));
  }
  __syncthreads();
  if (tid == 0) {
    float s = 0.0f;
    for (int t = 0; t < 33; ++t) s += g[t];
    gsum_s = s;
  }
  const int yc = y >> 3;
  if (tid < 28) row28[tid] = ps[(size_t)b * 784 + yc * 28 + tid];
  __syncthreads();
  if (tid < 224) {
    float acc = 0.0f;
#pragma unroll
    for (int t = 0; t < 33; ++t) {
      int xx = tid + t - 16;
      xx = xx < 0 ? -xx : (xx > 223 ? 446 - xx : xx);
      acc += g[t] * row28[xx >> 3];
    }
    tmp[((size_t)b * 224 + y) * 224 + tid] = acc / gsum_s;
  }
}

__global__ __launch_bounds__(256) void blur_v(const float* __restrict__ tmp,
                                              float* __restrict__ out) {
  const int y = blockIdx.x, b = blockIdx.y;
  __shared__ float g[33];
  __shared__ float gsum_s;
  const int tid = threadIdx.x;
  if (tid < 33) {
    float d = (float)tid - 16.0f;
    g[tid] = expf(-(d * d) * (1.0f / 32.0f));
  }
  __syncthreads();
  if (tid == 0) {
    float s = 0.0f;
    for (int t = 0; t < 33; ++t) s += g[t];
    gsum_s = s;
  }
  __syncthreads();
  if (tid < 224) {
    float acc = 0.0f;
#pragma unroll
    for (int t = 0; t < 33; ++t) {
      int yy = y + t - 16;
      yy = yy < 0 ? -yy : (yy > 223 ? 446 - yy : yy);
      acc += g[t] * tmp[((size_t)b * 224 + yy) * 224 + tid];
    }
    out[((size_t)b * 224 + y) * 224 + tid] = acc / gsum_s;
  }
}

// ---------------------------------------------------------------------------
extern "C" void kernel_launch(void* const* d_in, const int* in_sizes, int n_in,
                              void* d_out, int out_size, void* d_ws,
                              size_t ws_size, hipStream_t stream) {
  const float* emb = (const float*)d_in[0];
  const float* bank = (const float*)d_in[1];
  const int N = in_sizes[0] / C;  // 12544
  const int M = in_sizes[1] / C;  // 16384
  const int B = 16;               // = out_size / (224*224 + 1)

  float* ws = (float*)d_ws;
  float* anorm = ws;                       // N
  float* bnorm = anorm + N;                // M
  float* pvals = bnorm + M;                // 4N
  int* pidx = (int*)(pvals + 4 * (size_t)N);  // 4N
  float* ps = (float*)(pidx + 4 * (size_t)N); // N
  int* loc = (int*)(ps + N);               // N
  float* score = (float*)(loc + N);        // B
  int* nnidx = (int*)(score + B);          // B
  int* maxrow = nnidx + B;                 // B
  float* tmp = (float*)(maxrow + B);       // B*224*224

  float* out_map = (float*)d_out;
  float* out_pred = out_map + (size_t)B * 224 * 224;

  norms_kernel<<<(N + M + 255) / 256, 256, 0, stream>>>(emb, bank, anorm,
                                                        bnorm, N, M);
  nn_partial<<<dim3(N / 64, 4), 256, 0, stream>>>(emb, bank, bnorm, pvals,
                                                  pidx, N, M);
  nn_merge<<<(N + 255) / 256, 256, 0, stream>>>(anorm, pvals, pidx, ps, loc, N);
  batch_argmax<<<B, 256, 0, stream>>>(ps, loc, score, nnidx, maxrow);
  batch_rescore<<<B, 256, 0, stream>>>(emb, bank, bnorm, score, nnidx, maxrow,
                                       out_pred, M);
  blur_h<<<dim3(224, B), 256, 0, stream>>>(ps, tmp);
  blur_v<<<dim3(224, B), 256, 0, stream>>>(tmp, out_map);
}

// Round 3
// 436.894 us; speedup vs baseline: 3.3230x; 3.3230x over previous
//
#include <hip/hip_runtime.h>
#include <math.h>

#define C 128

typedef __attribute__((ext_vector_type(8))) short short8;     // 8 bf16 (4 VGPRs)
typedef __attribute__((ext_vector_type(4))) float f32x4;
typedef __attribute__((ext_vector_type(4))) unsigned int uint4v;
typedef unsigned short u16;

static __device__ __forceinline__ u16 f2bf(float f) {
  unsigned int u = __builtin_bit_cast(unsigned int, f);
  unsigned int r = (u + 0x7fffu + ((u >> 16) & 1u)) >> 16;
  return (u16)r;
}

// ---------------------------------------------------------------------------
// K0a: fp32 -> bf16 conversion of embedding and bank (8 elems/thread)
// ---------------------------------------------------------------------------
__global__ __launch_bounds__(256) void to_bf16(
    const float* __restrict__ A, const float* __restrict__ Bk,
    u16* __restrict__ Abf, u16* __restrict__ Bbf, int nA, int nB) {
  int t = blockIdx.x * 256 + threadIdx.x;
  int na8 = nA >> 3, nb8 = nB >> 3;
  if (t >= na8 + nb8) return;
  const float* src;
  u16* dst;
  size_t base;
  if (t < na8) { src = A; dst = Abf; base = (size_t)t << 3; }
  else { src = Bk; dst = Bbf; base = (size_t)(t - na8) << 3; }
  float4 v0 = *(const float4*)(src + base);
  float4 v1 = *(const float4*)(src + base + 4);
  u16 o[8] = {f2bf(v0.x), f2bf(v0.y), f2bf(v0.z), f2bf(v0.w),
              f2bf(v1.x), f2bf(v1.y), f2bf(v1.z), f2bf(v1.w)};
  *(uint4v*)(dst + base) = *(const uint4v*)o;
}

// ---------------------------------------------------------------------------
// K0b: row norms (fp32, exact)
// ---------------------------------------------------------------------------
__global__ __launch_bounds__(256) void norms_kernel(
    const float* __restrict__ A, const float* __restrict__ Bk,
    float* __restrict__ anorm, float* __restrict__ bnorm, int N, int M) {
  int t = blockIdx.x * 256 + threadIdx.x;
  const float* src;
  float* dst;
  int r;
  if (t < M) { src = Bk; dst = bnorm; r = t; }
  else if (t < M + N) { src = A; dst = anorm; r = t - M; }
  else return;
  const float4* p = (const float4*)(src + (size_t)r * C);
  float acc = 0.0f;
#pragma unroll
  for (int kc = 0; kc < C / 4; ++kc) {
    float4 v = p[kc];
    acc += v.x * v.x + v.y * v.y + v.z * v.z + v.w * v.w;
  }
  dst[r] = acc;
}

// ---------------------------------------------------------------------------
// K1: MFMA NN search.  grid (N/128, 8).  Block: 128 emb rows x 2048 bank rows.
// 4 waves in a 2x2 grid, each 64x64 output via 4x4 fragments of
// mfma_f32_16x16x32_bf16.  Tracks running min of (bnorm[j] - 2*dot) + argmin.
// Cross-wave (column-half) merge via LDS at the end — waves wc=0 and wc=1
// cover disjoint column halves of each tile and MUST be reduced, not raced.
// ---------------------------------------------------------------------------
__global__ __launch_bounds__(256, 2) void nn_mfma(
    const u16* __restrict__ Abf, const u16* __restrict__ Bbf,
    const float* __restrict__ bnorm, float* __restrict__ pvals,
    int* __restrict__ pidx, int N, int M) {
  __shared__ short As[128][136];   // +8 pad: 272B row stride
  __shared__ short Bs[128][136];
  const int tid = threadIdx.x;
  const int lane = tid & 63;
  const int w = tid >> 6;
  const int wr = w >> 1, wc = w & 1;     // 2x2 wave grid
  const int lr = lane & 15, kg = lane >> 4;
  const int row0 = blockIdx.x * 128;
  const int jchunk = M >> 3;             // 2048
  const int j0base = blockIdx.y * jchunk;

  // stage A tile once (each thread: half a row = 64 bf16 = 8 x 16B)
  {
    const int r = tid >> 1, h = tid & 1;
    const uint4v* src = (const uint4v*)(Abf + (size_t)(row0 + r) * C + h * 64);
    uint4v* dst = (uint4v*)&As[r][h * 64];
#pragma unroll
    for (int q = 0; q < 8; ++q) dst[q] = src[q];
  }
  __syncthreads();

  // hoist A fragments: af[fi][kstep]; lane holds A[row=lr][kstep*32+kg*8 ..+8]
  short8 af[4][4];
#pragma unroll
  for (int fi = 0; fi < 4; ++fi)
#pragma unroll
    for (int k = 0; k < 4; ++k)
      af[fi][k] = *(const short8*)&As[wr * 64 + fi * 16 + lr][k * 32 + kg * 8];

  float minv[16];
  int mini[16];
#pragma unroll
  for (int s = 0; s < 16; ++s) { minv[s] = INFINITY; mini[s] = 0x7fffffff; }

  for (int jt = 0; jt < jchunk; jt += 128) {
    const int j0 = j0base + jt;
    __syncthreads();   // all waves done reading previous Bs
    {
      const int r = tid >> 1, h = tid & 1;
      const uint4v* src = (const uint4v*)(Bbf + (size_t)(j0 + r) * C + h * 64);
      uint4v* dst = (uint4v*)&Bs[r][h * 64];
#pragma unroll
      for (int q = 0; q < 8; ++q) dst[q] = src[q];
    }
    __syncthreads();

    f32x4 acc[4][4];
#pragma unroll
    for (int fi = 0; fi < 4; ++fi)
#pragma unroll
      for (int fj = 0; fj < 4; ++fj) {
        f32x4 z = {0.0f, 0.0f, 0.0f, 0.0f};
        acc[fi][fj] = z;
      }

#pragma unroll
    for (int k = 0; k < 4; ++k) {
      short8 bf[4];
#pragma unroll
      for (int fj = 0; fj < 4; ++fj)
        bf[fj] = *(const short8*)&Bs[wc * 64 + fj * 16 + lr][k * 32 + kg * 8];
#pragma unroll
      for (int fi = 0; fi < 4; ++fi)
#pragma unroll
        for (int fj = 0; fj < 4; ++fj)
          acc[fi][fj] = __builtin_amdgcn_mfma_f32_16x16x32_bf16(
              af[fi][k], bf[fj], acc[fi][fj], 0, 0, 0);
    }

    // epilogue: v = bnorm[col] - 2*dot ; running (min, argmin)
    // C/D layout: col = lane&15 (=lr), row = (lane>>4)*4 + reg  (m89/m91)
#pragma unroll
    for (int fj = 0; fj < 4; ++fj) {
      const int col = j0 + wc * 64 + fj * 16 + lr;
      const float bn = bnorm[col];
#pragma unroll
      for (int fi = 0; fi < 4; ++fi) {
#pragma unroll
        for (int r = 0; r < 4; ++r) {
          float v = fmaf(-2.0f, acc[fi][fj][r], bn);
          const int s = fi * 4 + r;
          if (v < minv[s]) { minv[s] = v; mini[s] = col; }
        }
      }
    }
  }

  // reduce: butterfly across the 16 col-classes (lane bits 0..3), then
  // cross-wave merge of the two column halves (wc=0 / wc=1) via LDS.
  __syncthreads();                    // done with As/Bs — reuse as scratch
  float* rv = (float*)&As[0][0];      // [128][2]
  int* ri = (int*)&Bs[0][0];          // [128][2]
#pragma unroll
  for (int s = 0; s < 16; ++s) {
    float v = minv[s];
    int ix = mini[s];
#pragma unroll
    for (int m = 1; m <= 8; m <<= 1) {
      float ov = __shfl_xor(v, m, 64);
      int oi = __shfl_xor(ix, m, 64);
      if (ov < v || (ov == v && oi < ix)) { v = ov; ix = oi; }
    }
    if (lr == 0) {
      const int row = wr * 64 + (s >> 2) * 16 + kg * 4 + (s & 3);
      rv[row * 2 + wc] = v;
      ri[row * 2 + wc] = ix;
    }
  }
  __syncthreads();
  if (tid < 128) {
    float v0 = rv[tid * 2], v1 = rv[tid * 2 + 1];
    int i0 = ri[tid * 2], i1 = ri[tid * 2 + 1];
    bool take1 = (v1 < v0) || (v1 == v0 && i1 < i0);
    pvals[(size_t)blockIdx.y * N + row0 + tid] = take1 ? v1 : v0;
    pidx[(size_t)blockIdx.y * N + row0 + tid] = take1 ? i1 : i0;
  }
}

// ---------------------------------------------------------------------------
// K2: merge 8 partials, add anorm, sqrt -> patch_scores + locations
// ---------------------------------------------------------------------------
__global__ __launch_bounds__(256) void nn_merge(
    const float* __restrict__ anorm, const float* __restrict__ pvals,
    const int* __restrict__ pidx, float* __restrict__ ps,
    int* __restrict__ loc, int N) {
  int i = blockIdx.x * 256 + threadIdx.x;
  if (i >= N) return;
  float bv = INFINITY;
  int bi_ = 0x7fffffff;
  for (int p = 0; p < 8; ++p) {
    float v = pvals[(size_t)p * N + i];
    int ix = pidx[(size_t)p * N + i];
    if (v < bv || (v == bv && ix < bi_)) { bv = v; bi_ = ix; }
  }
  float d2 = anorm[i] + bv;
  ps[i] = sqrtf(fmaxf(d2, 1e-12f));
  loc[i] = bi_;
}

// ---------------------------------------------------------------------------
// K3: per-image argmax of patch scores (first occurrence)
// ---------------------------------------------------------------------------
__global__ __launch_bounds__(256) void batch_argmax(
    const float* __restrict__ ps, const int* __restrict__ loc,
    float* __restrict__ score, int* __restrict__ nnidx,
    int* __restrict__ maxrow) {
  const int b = blockIdx.x;
  __shared__ float sv[256];
  __shared__ int si[256];
  const int tid = threadIdx.x;
  float bv = -INFINITY;
  int bi_ = 0x7fffffff;
  for (int i = tid; i < 784; i += 256) {
    float v = ps[(size_t)b * 784 + i];
    if (v > bv) { bv = v; bi_ = i; }
  }
  sv[tid] = bv; si[tid] = bi_;
  __syncthreads();
  for (int s = 128; s > 0; s >>= 1) {
    if (tid < s) {
      if (sv[tid + s] > sv[tid] ||
          (sv[tid + s] == sv[tid] && si[tid + s] < si[tid])) {
        sv[tid] = sv[tid + s]; si[tid] = si[tid + s];
      }
    }
    __syncthreads();
  }
  if (tid == 0) {
    score[b] = sv[0];
    int p = si[0];
    maxrow[b] = b * 784 + p;
    nnidx[b] = loc[(size_t)b * 784 + p];
  }
}

// ---------------------------------------------------------------------------
// K4: per-image rescore (exact fp32): d(nn_sample, bank), top-9, softmax
// ---------------------------------------------------------------------------
__global__ __launch_bounds__(256) void batch_rescore(
    const float* __restrict__ emb, const float* __restrict__ Bk,
    const float* __restrict__ bnorm, const float* __restrict__ score,
    const int* __restrict__ nnidx, const int* __restrict__ maxrow,
    float* __restrict__ pred, int M) {
  const int b = blockIdx.x;
  __shared__ float d2s[16384];
  __shared__ float vec[C];
  __shared__ float sv[256];
  __shared__ int si[256];
  __shared__ float ds[9];
  __shared__ int sup[9];
  const int tid = threadIdx.x;
  const int nn = nnidx[b];
  if (tid < C) vec[tid] = Bk[(size_t)nn * C + tid];
  __syncthreads();
  const float nnorm = bnorm[nn];
  for (int j = tid; j < M; j += 256) {
    const float4* br = (const float4*)(Bk + (size_t)j * C);
    float dot = 0.0f;
#pragma unroll
    for (int kc = 0; kc < C / 4; ++kc) {
      float4 v = br[kc];
      float4 w = *(const float4*)&vec[kc * 4];
      dot += v.x * w.x + v.y * w.y + v.z * w.z + v.w * w.w;
    }
    d2s[j] = nnorm + bnorm[j] - 2.0f * dot;
  }
  __syncthreads();
  for (int s9 = 0; s9 < 9; ++s9) {
    float bv = INFINITY;
    int bi_ = 0x7fffffff;
    for (int j = tid; j < M; j += 256) {
      float v = d2s[j];
      if (v < bv) { bv = v; bi_ = j; }
    }
    sv[tid] = bv; si[tid] = bi_;
    __syncthreads();
    for (int s = 128; s > 0; s >>= 1) {
      if (tid < s) {
        if (sv[tid + s] < sv[tid] ||
            (sv[tid + s] == sv[tid] && si[tid + s] < si[tid])) {
          sv[tid] = sv[tid + s]; si[tid] = si[tid + s];
        }
      }
      __syncthreads();
    }
    if (tid == 0) { sup[s9] = si[0]; d2s[si[0]] = INFINITY; }
    __syncthreads();
  }
  if (tid < C) vec[tid] = emb[(size_t)maxrow[b] * C + tid];
  __syncthreads();
  if (tid < 9) {
    const float* br = Bk + (size_t)sup[tid] * C;
    float acc = 0.0f;
    for (int k = 0; k < C; ++k) {
      float d = vec[k] - br[k];
      acc += d * d;
    }
    ds[tid] = sqrtf(fmaxf(acc, 1e-12f));
  }
  __syncthreads();
  if (tid == 0) {
    float m = ds[0];
    for (int t = 1; t < 9; ++t) m = fmaxf(m, ds[t]);
    float sum = 0.0f, e0 = 0.0f;
    for (int t = 0; t < 9; ++t) {
      float e = expf(ds[t] - m);
      sum += e;
      if (t == 0) e0 = e;
    }
    pred[b] = (1.0f - e0 / sum) * score[b];
  }
}

// ---------------------------------------------------------------------------
// K5/K6: upsample 28x28 -> 224x224 fused with separable 33-tap blur (reflect)
// ---------------------------------------------------------------------------
__global__ __launch_bounds__(256) void blur_h(const float* __restrict__ ps,
                                              float* __restrict__ tmp) {
  const int y = blockIdx.x, b = blockIdx.y;
  __shared__ float g[33];
  __shared__ float row28[28];
  __shared__ float gsum_s;
  const int tid = threadIdx.x;
  if (tid < 33) {
    float d = (float)tid - 16.0f;
    g[tid] = expf(-(d * d) * (1.0f / 32.0f));
  }
  __syncthreads();
  if (tid == 0) {
    float s = 0.0f;
    for (int t = 0; t < 33; ++t) s += g[t];
    gsum_s = s;
  }
  const int yc = y >> 3;
  if (tid < 28) row28[tid] = ps[(size_t)b * 784 + yc * 28 + tid];
  __syncthreads();
  if (tid < 224) {
    float acc = 0.0f;
#pragma unroll
    for (int t = 0; t < 33; ++t) {
      int xx = tid + t - 16;
      xx = xx < 0 ? -xx : (xx > 223 ? 446 - xx : xx);
      acc += g[t] * row28[xx >> 3];
    }
    tmp[((size_t)b * 224 + y) * 224 + tid] = acc / gsum_s;
  }
}

__global__ __launch_bounds__(256) void blur_v(const float* __restrict__ tmp,
                                              float* __restrict__ out) {
  const int y = blockIdx.x, b = blockIdx.y;
  __shared__ float g[33];
  __shared__ float gsum_s;
  const int tid = threadIdx.x;
  if (tid < 33) {
    float d = (float)tid - 16.0f;
    g[tid] = expf(-(d * d) * (1.0f / 32.0f));
  }
  __syncthreads();
  if (tid == 0) {
    float s = 0.0f;
    for (int t = 0; t < 33; ++t) s += g[t];
    gsum_s = s;
  }
  __syncthreads();
  if (tid < 224) {
    float acc = 0.0f;
#pragma unroll
    for (int t = 0; t < 33; ++t) {
      int yy = y + t - 16;
      yy = yy < 0 ? -yy : (yy > 223 ? 446 - yy : yy);
      acc += g[t] * tmp[((size_t)b * 224 + yy) * 224 + tid];
    }
    out[((size_t)b * 224 + y) * 224 + tid] = acc / gsum_s;
  }
}

// ---------------------------------------------------------------------------
extern "C" void kernel_launch(void* const* d_in, const int* in_sizes, int n_in,
                              void* d_out, int out_size, void* d_ws,
                              size_t ws_size, hipStream_t stream) {
  const float* emb = (const float*)d_in[0];
  const float* bank = (const float*)d_in[1];
  const int N = in_sizes[0] / C;  // 12544
  const int M = in_sizes[1] / C;  // 16384
  const int B = 16;

  u16* Abf = (u16*)d_ws;                          // N*C bf16
  u16* Bbf = Abf + (size_t)N * C;                 // M*C bf16
  float* anorm = (float*)(Bbf + (size_t)M * C);   // N
  float* bnorm = anorm + N;                       // M
  float* pvals = bnorm + M;                       // 8N
  int* pidx = (int*)(pvals + 8 * (size_t)N);      // 8N
  float* ps = (float*)(pidx + 8 * (size_t)N);     // N
  int* loc = (int*)(ps + N);                      // N
  float* score = (float*)(loc + N);               // B
  int* nnidx = (int*)(score + B);                 // B
  int* maxrow = nnidx + B;                        // B
  float* tmp = (float*)(maxrow + B);              // B*224*224

  float* out_map = (float*)d_out;
  float* out_pred = out_map + (size_t)B * 224 * 224;

  const int nconv = ((N + M) * C) / 8;
  to_bf16<<<(nconv + 255) / 256, 256, 0, stream>>>(emb, bank, Abf, Bbf, N * C,
                                                   M * C);
  norms_kernel<<<(N + M + 255) / 256, 256, 0, stream>>>(emb, bank, anorm,
                                                        bnorm, N, M);
  nn_mfma<<<dim3(N / 128, 8), 256, 0, stream>>>(Abf, Bbf, bnorm, pvals, pidx,
                                                N, M);
  nn_merge<<<(N + 255) / 256, 256, 0, stream>>>(anorm, pvals, pidx, ps, loc, N);
  batch_argmax<<<B, 256, 0, stream>>>(ps, loc, score, nnidx, maxrow);
  batch_rescore<<<B, 256, 0, stream>>>(emb, bank, bnorm, score, nnidx, maxrow,
                                       out_pred, M);
  blur_h<<<dim3(224, B), 256, 0, stream>>>(ps, tmp);
  blur_v<<<dim3(224, B), 256, 0, stream>>>(tmp, out_map);
}

// Round 4
// 211.549 us; speedup vs baseline: 6.8627x; 2.0652x over previous
//
#include <hip/hip_runtime.h>
#include <math.h>

#define C 128

typedef __attribute__((ext_vector_type(8))) short short8;     // 8 bf16 (4 VGPRs)
typedef __attribute__((ext_vector_type(4))) float f32x4;
typedef __attribute__((ext_vector_type(4))) unsigned int uint4v;
typedef unsigned short u16;

static __device__ __forceinline__ u16 f2bf(float f) {
  unsigned int u = __builtin_bit_cast(unsigned int, f);
  unsigned int r = (u + 0x7fffu + ((u >> 16) & 1u)) >> 16;
  return (u16)r;
}

// ---------------------------------------------------------------------------
// K0: fused fp32->bf16 convert + row norms.  One 8-float chunk per thread,
// 16 threads per row; row-norm via 4-step shfl_xor within the 16-lane group.
// ---------------------------------------------------------------------------
__global__ __launch_bounds__(256) void prep_kernel(
    const float* __restrict__ emb, const float* __restrict__ bank,
    u16* __restrict__ Abf, u16* __restrict__ Bbf, float* __restrict__ anorm,
    float* __restrict__ bnorm, int N, int M) {
  const int tid = threadIdx.x;
  const size_t chunk = (size_t)blockIdx.x * 256 + tid;
  const size_t total = (size_t)(N + M) * (C / 8);
  if (chunk >= total) return;
  const int gr = (int)(chunk >> 4);       // 16 chunks per 128-elem row
  const int co = (int)(chunk & 15) * 8;
  const float* src;
  u16* dst;
  float* ndst;
  int r;
  if (gr < N) { src = emb; dst = Abf; ndst = anorm; r = gr; }
  else { src = bank; dst = Bbf; ndst = bnorm; r = gr - N; }
  const float* p = src + (size_t)r * C + co;
  float4 v0 = *(const float4*)p;
  float4 v1 = *(const float4*)(p + 4);
  u16 o[8] = {f2bf(v0.x), f2bf(v0.y), f2bf(v0.z), f2bf(v0.w),
              f2bf(v1.x), f2bf(v1.y), f2bf(v1.z), f2bf(v1.w)};
  *(uint4v*)(dst + (size_t)r * C + co) = *(const uint4v*)o;
  float s = v0.x * v0.x + v0.y * v0.y + v0.z * v0.z + v0.w * v0.w +
            v1.x * v1.x + v1.y * v1.y + v1.z * v1.z + v1.w * v1.w;
#pragma unroll
  for (int m = 1; m <= 8; m <<= 1) s += __shfl_xor(s, m, 64);
  if ((tid & 15) == 0) ndst[r] = s;
}

// ---------------------------------------------------------------------------
// K1: MFMA NN search.  grid (N/128, 8).  Block: 128 emb rows x 2048 bank rows.
// 4 waves in a 2x2 grid, each 64x64 output via 4x4 fragments of
// mfma_f32_16x16x32_bf16.  Running min of (bnorm[j] - 2*dot) + argmin;
// cross-wave column-half merge via LDS at the end.
// ---------------------------------------------------------------------------
__global__ __launch_bounds__(256, 2) void nn_mfma(
    const u16* __restrict__ Abf, const u16* __restrict__ Bbf,
    const float* __restrict__ bnorm, float* __restrict__ pvals,
    int* __restrict__ pidx, int N, int M) {
  __shared__ short As[128][136];   // +8 pad: 272B row stride
  __shared__ short Bs[128][136];
  const int tid = threadIdx.x;
  const int lane = tid & 63;
  const int w = tid >> 6;
  const int wr = w >> 1, wc = w & 1;     // 2x2 wave grid
  const int lr = lane & 15, kg = lane >> 4;
  const int row0 = blockIdx.x * 128;
  const int jchunk = M >> 3;             // 2048
  const int j0base = blockIdx.y * jchunk;

  {
    const int r = tid >> 1, h = tid & 1;
    const uint4v* src = (const uint4v*)(Abf + (size_t)(row0 + r) * C + h * 64);
    uint4v* dst = (uint4v*)&As[r][h * 64];
#pragma unroll
    for (int q = 0; q < 8; ++q) dst[q] = src[q];
  }
  __syncthreads();

  short8 af[4][4];
#pragma unroll
  for (int fi = 0; fi < 4; ++fi)
#pragma unroll
    for (int k = 0; k < 4; ++k)
      af[fi][k] = *(const short8*)&As[wr * 64 + fi * 16 + lr][k * 32 + kg * 8];

  float minv[16];
  int mini[16];
#pragma unroll
  for (int s = 0; s < 16; ++s) { minv[s] = INFINITY; mini[s] = 0x7fffffff; }

  for (int jt = 0; jt < jchunk; jt += 128) {
    const int j0 = j0base + jt;
    __syncthreads();
    {
      const int r = tid >> 1, h = tid & 1;
      const uint4v* src = (const uint4v*)(Bbf + (size_t)(j0 + r) * C + h * 64);
      uint4v* dst = (uint4v*)&Bs[r][h * 64];
#pragma unroll
      for (int q = 0; q < 8; ++q) dst[q] = src[q];
    }
    __syncthreads();

    f32x4 acc[4][4];
#pragma unroll
    for (int fi = 0; fi < 4; ++fi)
#pragma unroll
      for (int fj = 0; fj < 4; ++fj) {
        f32x4 z = {0.0f, 0.0f, 0.0f, 0.0f};
        acc[fi][fj] = z;
      }

#pragma unroll
    for (int k = 0; k < 4; ++k) {
      short8 bf[4];
#pragma unroll
      for (int fj = 0; fj < 4; ++fj)
        bf[fj] = *(const short8*)&Bs[wc * 64 + fj * 16 + lr][k * 32 + kg * 8];
#pragma unroll
      for (int fi = 0; fi < 4; ++fi)
#pragma unroll
        for (int fj = 0; fj < 4; ++fj)
          acc[fi][fj] = __builtin_amdgcn_mfma_f32_16x16x32_bf16(
              af[fi][k], bf[fj], acc[fi][fj], 0, 0, 0);
    }

    // C/D layout: col = lane&15 (=lr), row = (lane>>4)*4 + reg  (m89/m91)
#pragma unroll
    for (int fj = 0; fj < 4; ++fj) {
      const int col = j0 + wc * 64 + fj * 16 + lr;
      const float bn = bnorm[col];
#pragma unroll
      for (int fi = 0; fi < 4; ++fi) {
#pragma unroll
        for (int r = 0; r < 4; ++r) {
          float v = fmaf(-2.0f, acc[fi][fj][r], bn);
          const int s = fi * 4 + r;
          if (v < minv[s]) { minv[s] = v; mini[s] = col; }
        }
      }
    }
  }

  __syncthreads();                    // done with As/Bs — reuse as scratch
  float* rv = (float*)&As[0][0];      // [128][2]
  int* ri = (int*)&Bs[0][0];          // [128][2]
#pragma unroll
  for (int s = 0; s < 16; ++s) {
    float v = minv[s];
    int ix = mini[s];
#pragma unroll
    for (int m = 1; m <= 8; m <<= 1) {
      float ov = __shfl_xor(v, m, 64);
      int oi = __shfl_xor(ix, m, 64);
      if (ov < v || (ov == v && oi < ix)) { v = ov; ix = oi; }
    }
    if (lr == 0) {
      const int row = wr * 64 + (s >> 2) * 16 + kg * 4 + (s & 3);
      rv[row * 2 + wc] = v;
      ri[row * 2 + wc] = ix;
    }
  }
  __syncthreads();
  if (tid < 128) {
    float v0 = rv[tid * 2], v1 = rv[tid * 2 + 1];
    int i0 = ri[tid * 2], i1 = ri[tid * 2 + 1];
    bool take1 = (v1 < v0) || (v1 == v0 && i1 < i0);
    pvals[(size_t)blockIdx.y * N + row0 + tid] = take1 ? v1 : v0;
    pidx[(size_t)blockIdx.y * N + row0 + tid] = take1 ? i1 : i0;
  }
}

// ---------------------------------------------------------------------------
// K2: merge 8 partials, add anorm, sqrt -> patch_scores + locations
// ---------------------------------------------------------------------------
__global__ __launch_bounds__(256) void nn_merge(
    const float* __restrict__ anorm, const float* __restrict__ pvals,
    const int* __restrict__ pidx, float* __restrict__ ps,
    int* __restrict__ loc, int N) {
  int i = blockIdx.x * 256 + threadIdx.x;
  if (i >= N) return;
  float bv = INFINITY;
  int bi_ = 0x7fffffff;
  for (int p = 0; p < 8; ++p) {
    float v = pvals[(size_t)p * N + i];
    int ix = pidx[(size_t)p * N + i];
    if (v < bv || (v == bv && ix < bi_)) { bv = v; bi_ = ix; }
  }
  float d2 = anorm[i] + bv;
  ps[i] = sqrtf(fmaxf(d2, 1e-12f));
  loc[i] = bi_;
}

// ---------------------------------------------------------------------------
// K3: per-image argmax of patch scores (first occurrence)
// ---------------------------------------------------------------------------
__global__ __launch_bounds__(256) void batch_argmax(
    const float* __restrict__ ps, const int* __restrict__ loc,
    float* __restrict__ score, int* __restrict__ nnidx,
    int* __restrict__ maxrow) {
  const int b = blockIdx.x;
  __shared__ float sv[256];
  __shared__ int si[256];
  const int tid = threadIdx.x;
  float bv = -INFINITY;
  int bi_ = 0x7fffffff;
  for (int i = tid; i < 784; i += 256) {
    float v = ps[(size_t)b * 784 + i];
    if (v > bv) { bv = v; bi_ = i; }
  }
  sv[tid] = bv; si[tid] = bi_;
  __syncthreads();
  for (int s = 128; s > 0; s >>= 1) {
    if (tid < s) {
      if (sv[tid + s] > sv[tid] ||
          (sv[tid + s] == sv[tid] && si[tid + s] < si[tid])) {
        sv[tid] = sv[tid + s]; si[tid] = si[tid + s];
      }
    }
    __syncthreads();
  }
  if (tid == 0) {
    score[b] = sv[0];
    int p = si[0];
    maxrow[b] = b * 784 + p;
    nnidx[b] = loc[(size_t)b * 784 + p];
  }
}

// ---------------------------------------------------------------------------
// K4a: per-(image, bank-chunk) top-9 candidates.  grid (8, B), block 256.
// Each thread keeps its 8 (d2, j) pairs in registers; 9 parallel argmin
// passes with LDS tree reduce; candidates -> global.
// ---------------------------------------------------------------------------
__global__ __launch_bounds__(256) void rescore_part(
    const float* __restrict__ Bk, const float* __restrict__ bnorm,
    const int* __restrict__ nnidx, float* __restrict__ cvals,
    int* __restrict__ cidx, int M) {
  const int c = blockIdx.x;   // chunk
  const int b = blockIdx.y;   // image
  const int tid = threadIdx.x;
  __shared__ float vec[C];
  __shared__ float sv[256];
  __shared__ int si[256];
  const int nn = nnidx[b];
  if (tid < 32)
    *(float4*)&vec[tid * 4] = *(const float4*)(Bk + (size_t)nn * C + tid * 4);
  __syncthreads();
  const float nnorm = bnorm[nn];
  const int j0 = c * (M >> 3);
  float rv[8];
  int rj[8];
#pragma unroll
  for (int q = 0; q < 8; ++q) {
    const int j = j0 + q * 256 + tid;
    const float4* br = (const float4*)(Bk + (size_t)j * C);
    float dot = 0.0f;
#pragma unroll
    for (int kc = 0; kc < 32; ++kc) {
      float4 v = br[kc];
      float4 ww = *(const float4*)&vec[kc * 4];
      dot += v.x * ww.x + v.y * ww.y + v.z * ww.z + v.w * ww.w;
    }
    rv[q] = nnorm + bnorm[j] - 2.0f * dot;
    rj[q] = j;
  }
  for (int s9 = 0; s9 < 9; ++s9) {
    float bv = INFINITY;
    int bj = 0x7fffffff;
#pragma unroll
    for (int q = 0; q < 8; ++q)
      if (rv[q] < bv) { bv = rv[q]; bj = rj[q]; }  // ascending j keeps first
    sv[tid] = bv; si[tid] = bj;
    __syncthreads();
    for (int s = 128; s > 0; s >>= 1) {
      if (tid < s) {
        if (sv[tid + s] < sv[tid] ||
            (sv[tid + s] == sv[tid] && si[tid + s] < si[tid])) {
          sv[tid] = sv[tid + s]; si[tid] = si[tid + s];
        }
      }
      __syncthreads();
    }
    const int selj = si[0];
    if (tid == 0) {
      cvals[((size_t)b * 8 + c) * 9 + s9] = sv[0];
      cidx[((size_t)b * 8 + c) * 9 + s9] = selj;
    }
#pragma unroll
    for (int q = 0; q < 8; ++q)
      if (rj[q] == selj) rv[q] = INFINITY;
    __syncthreads();
  }
}

// ---------------------------------------------------------------------------
// K4b: merge 72 candidates -> exact top-9, support distances, softmax.
// grid B, block 128 (2 waves).
// ---------------------------------------------------------------------------
__global__ __launch_bounds__(128) void rescore_merge(
    const float* __restrict__ emb, const float* __restrict__ Bk,
    const float* __restrict__ cvals, const int* __restrict__ cidx,
    const float* __restrict__ score, const int* __restrict__ maxrow,
    float* __restrict__ pred) {
  const int b = blockIdx.x;
  const int tid = threadIdx.x;
  const int w = tid >> 6, lane = tid & 63;
  __shared__ float wv[72];
  __shared__ int wi[72];
  __shared__ float sv[128];
  __shared__ int si[128];
  __shared__ int sp[128];
  __shared__ int sup[9];
  __shared__ float vec[C];
  __shared__ float ds[9];
  if (tid < 72) {
    wv[tid] = cvals[(size_t)b * 72 + tid];
    wi[tid] = cidx[(size_t)b * 72 + tid];
  }
  if (tid < 32)
    *(float4*)&vec[tid * 4] =
        *(const float4*)(emb + (size_t)maxrow[b] * C + tid * 4);
  __syncthreads();
  for (int s9 = 0; s9 < 9; ++s9) {
    if (tid < 72) { sv[tid] = wv[tid]; si[tid] = wi[tid]; sp[tid] = tid; }
    else { sv[tid] = INFINITY; si[tid] = 0x7fffffff; sp[tid] = -1; }
    __syncthreads();
    for (int s = 64; s > 0; s >>= 1) {
      if (tid < s) {
        if (sv[tid + s] < sv[tid] ||
            (sv[tid + s] == sv[tid] && si[tid + s] < si[tid])) {
          sv[tid] = sv[tid + s]; si[tid] = si[tid + s]; sp[tid] = sp[tid + s];
        }
      }
      __syncthreads();
    }
    if (tid == 0) {
      sup[s9] = si[0];
      wv[sp[0]] = INFINITY;
    }
    __syncthreads();
  }
  // support distances: wave w handles supports s = w, w+2, ...
  for (int s = w; s < 9; s += 2) {
    const float* br = Bk + (size_t)sup[s] * C;
    float d0 = vec[lane * 2] - br[lane * 2];
    float d1 = vec[lane * 2 + 1] - br[lane * 2 + 1];
    float acc = d0 * d0 + d1 * d1;
#pragma unroll
    for (int m = 1; m <= 32; m <<= 1) acc += __shfl_xor(acc, m, 64);
    if (lane == 0) ds[s] = sqrtf(fmaxf(acc, 1e-12f));
  }
  __syncthreads();
  if (tid == 0) {
    float m = ds[0];
    for (int t = 1; t < 9; ++t) m = fmaxf(m, ds[t]);
    float sum = 0.0f, e0 = 0.0f;
    for (int t = 0; t < 9; ++t) {
      float e = expf(ds[t] - m);
      sum += e;
      if (t == 0) e0 = e;
    }
    pred[b] = (1.0f - e0 / sum) * score[b];
  }
}

// ---------------------------------------------------------------------------
// K5/K6: upsample 28x28 -> 224x224 fused with separable 33-tap blur (reflect)
// ---------------------------------------------------------------------------
__global__ __launch_bounds__(256) void blur_h(const float* __restrict__ ps,
                                              float* __restrict__ tmp) {
  const int y = blockIdx.x, b = blockIdx.y;
  __shared__ float g[33];
  __shared__ float row28[28];
  __shared__ float gsum_s;
  const int tid = threadIdx.x;
  if (tid < 33) {
    float d = (float)tid - 16.0f;
    g[tid] = expf(-(d * d) * (1.0f / 32.0f));
  }
  __syncthreads();
  if (tid == 0) {
    float s = 0.0f;
    for (int t = 0; t < 33; ++t) s += g[t];
    gsum_s = s;
  }
  const int yc = y >> 3;
  if (tid < 28) row28[tid] = ps[(size_t)b * 784 + yc * 28 + tid];
  __syncthreads();
  if (tid < 224) {
    float acc = 0.0f;
#pragma unroll
    for (int t = 0; t < 33; ++t) {
      int xx = tid + t - 16;
      xx = xx < 0 ? -xx : (xx > 223 ? 446 - xx : xx);
      acc += g[t] * row28[xx >> 3];
    }
    tmp[((size_t)b * 224 + y) * 224 + tid] = acc / gsum_s;
  }
}

__global__ __launch_bounds__(256) void blur_v(const float* __restrict__ tmp,
                                              float* __restrict__ out) {
  const int y = blockIdx.x, b = blockIdx.y;
  __shared__ float g[33];
  __shared__ float gsum_s;
  const int tid = threadIdx.x;
  if (tid < 33) {
    float d = (float)tid - 16.0f;
    g[tid] = expf(-(d * d) * (1.0f / 32.0f));
  }
  __syncthreads();
  if (tid == 0) {
    float s = 0.0f;
    for (int t = 0; t < 33; ++t) s += g[t];
    gsum_s = s;
  }
  __syncthreads();
  if (tid < 224) {
    float acc = 0.0f;
#pragma unroll
    for (int t = 0; t < 33; ++t) {
      int yy = y + t - 16;
      yy = yy < 0 ? -yy : (yy > 223 ? 446 - yy : yy);
      acc += g[t] * tmp[((size_t)b * 224 + yy) * 224 + tid];
    }
    out[((size_t)b * 224 + y) * 224 + tid] = acc / gsum_s;
  }
}

// ---------------------------------------------------------------------------
extern "C" void kernel_launch(void* const* d_in, const int* in_sizes, int n_in,
                              void* d_out, int out_size, void* d_ws,
                              size_t ws_size, hipStream_t stream) {
  const float* emb = (const float*)d_in[0];
  const float* bank = (const float*)d_in[1];
  const int N = in_sizes[0] / C;  // 12544
  const int M = in_sizes[1] / C;  // 16384
  const int B = 16;

  u16* Abf = (u16*)d_ws;                          // N*C bf16
  u16* Bbf = Abf + (size_t)N * C;                 // M*C bf16
  float* anorm = (float*)(Bbf + (size_t)M * C);   // N
  float* bnorm = anorm + N;                       // M
  float* pvals = bnorm + M;                       // 8N
  int* pidx = (int*)(pvals + 8 * (size_t)N);      // 8N
  float* ps = (float*)(pidx + 8 * (size_t)N);     // N
  int* loc = (int*)(ps + N);                      // N
  float* score = (float*)(loc + N);               // B
  int* nnidx = (int*)(score + B);                 // B
  int* maxrow = nnidx + B;                        // B
  float* cvals = (float*)(maxrow + B);            // B*72
  int* cidx = (int*)(cvals + B * 72);             // B*72
  float* tmp = (float*)(cidx + B * 72);           // B*224*224

  float* out_map = (float*)d_out;
  float* out_pred = out_map + (size_t)B * 224 * 224;

  const size_t nchunks = (size_t)(N + M) * (C / 8);
  prep_kernel<<<(int)((nchunks + 255) / 256), 256, 0, stream>>>(
      emb, bank, Abf, Bbf, anorm, bnorm, N, M);
  nn_mfma<<<dim3(N / 128, 8), 256, 0, stream>>>(Abf, Bbf, bnorm, pvals, pidx,
                                                N, M);
  nn_merge<<<(N + 255) / 256, 256, 0, stream>>>(anorm, pvals, pidx, ps, loc, N);
  batch_argmax<<<B, 256, 0, stream>>>(ps, loc, score, nnidx, maxrow);
  rescore_part<<<dim3(8, B), 256, 0, stream>>>(bank, bnorm, nnidx, cvals, cidx,
                                               M);
  rescore_merge<<<B, 128, 0, stream>>>(emb, bank, cvals, cidx, score, maxrow,
                                       out_pred);
  blur_h<<<dim3(224, B), 256, 0, stream>>>(ps, tmp);
  blur_v<<<dim3(224, B), 256, 0, stream>>>(tmp, out_map);
}